// Round 8
// baseline (54.405 us; speedup 1.0000x reference)
//
#include <hip/hip_runtime.h>
#include <hip/hip_bf16.h>

// QKVAttentionLegacy: B*H=32, C=64, T=S=2048, fp32 in/out, channels-first.
// Round 8: s-split wave pairs (sh in {0,1}) x t-quarters (64 t-rows/wave):
// each wave does 32s x 64t per tile -> 8 ds_read_b128/tile (was 16), 1:4
// K-frag reuse, same 32 MFMAs/tile/wave. Halves combined once at epilogue
// via LDS. Window structure (2 tiles per raw barrier + stale vmcnt) from R7.

typedef __attribute__((ext_vector_type(4))) float f32x4;
typedef __attribute__((ext_vector_type(8))) short bf16x8;
typedef __attribute__((ext_vector_type(4))) float float4_t;
typedef __attribute__((ext_vector_type(4))) unsigned u32x4;

__device__ __forceinline__ unsigned short f2bf(float f) {
  unsigned u = __builtin_bit_cast(unsigned, f);
  u += 0x7FFFu + ((u >> 16) & 1u);               // round-to-nearest-even
  return (unsigned short)(u >> 16);
}

__device__ __forceinline__ float exp2_fast(float x) {
  float r;
  asm("v_exp_f32 %0, %1" : "=v"(r) : "v"(x));
  return r;
}

__device__ __forceinline__ unsigned cvt_pk_bf16(float a, float b) {
  unsigned r;
  asm("v_cvt_pk_bf16_f32 %0, %1, %2" : "=v"(r) : "v"(a), "v"(b));
  return r;
}

#define GLOAD_LDS16(g, l) __builtin_amdgcn_global_load_lds(                 \
    (const __attribute__((address_space(1))) unsigned*)(g),                 \
    (__attribute__((address_space(3))) unsigned*)(l), 16, 0, 0)

// scale = 1/sqrt(sqrt(64)) per operand; sqrt(log2e) folded so S_mfma = S*log2e
#define SCL (0.35355339059327373f * 1.2011224087864498f)

// ---------------- pre-pass: f32 [bh][c][s] -> bf16 layouts ----------------
__global__ __launch_bounds__(256)
void prep(const float* __restrict__ qkv, const float* __restrict__ y,
          unsigned short* __restrict__ kT, unsigned short* __restrict__ v,
          unsigned short* __restrict__ qT) {
  __shared__ unsigned short tb[64][66];
  const int tid = threadIdx.x;
  const int isQ = blockIdx.x >> 10;
  const int b2  = blockIdx.x & 1023;
  const int bh  = b2 >> 5;
  const int s0  = (b2 & 31) * 64;
  const float* src = (isQ ? qkv : y) + (size_t)bh * 131072;

  const int c = tid >> 2, j = tid & 3;
  float fv[16];
  #pragma unroll
  for (int p = 0; p < 4; ++p) {
    float4_t a = *(const float4_t*)(src + c * 2048 + s0 + j * 16 + p * 4);
    #pragma unroll
    for (int i = 0; i < 4; ++i) fv[p * 4 + i] = a[i];
  }
  if (!isQ) {   // v: unscaled bf16, natural [c][s]
    bf16x8 u0, u1;
    #pragma unroll
    for (int i = 0; i < 8; ++i) { u0[i] = (short)f2bf(fv[i]); u1[i] = (short)f2bf(fv[8 + i]); }
    unsigned short* vp = v + (size_t)bh * 131072 + c * 2048 + s0 + j * 16;
    *(bf16x8*)(vp) = u0;
    *(bf16x8*)(vp + 8) = u1;
  }
  #pragma unroll
  for (int m = 0; m < 8; ++m) {
    unsigned lo = f2bf(fv[2 * m] * SCL);
    unsigned hi = f2bf(fv[2 * m + 1] * SCL);
    *(unsigned*)&tb[c][j * 16 + 2 * m] = lo | (hi << 16);
  }
  __syncthreads();

  const int srow = tid >> 2, i2 = tid & 3;
  unsigned short outv[16];
  #pragma unroll
  for (int m = 0; m < 16; ++m) outv[m] = tb[i2 * 16 + m][srow];
  unsigned short* dT = (isQ ? qT : kT) + (size_t)bh * 131072 +
                       (size_t)(s0 + srow) * 64 + i2 * 16;
  *(bf16x8*)(dT)     = *(bf16x8*)&outv[0];
  *(bf16x8*)(dT + 8) = *(bf16x8*)&outv[8];
}

// ---------------- main kernel: s-split wave pairs, 2-tile windows ----------
#define WBS 32768        // window bufset: K_A(8K) K_B(8K) V_A(8K) V_B(8K)
#define EP_STR 66        // epilogue O stride (f32)
#define EP_W2  16896     // 64 * 66 * 4 bytes per t-quarter
#define LSUM_OFF 67584   // [8 w][4 tg][16] f32 = 2 KB
#define SMEM_SZ 69632

__global__ __launch_bounds__(512, 2)
void attn_main(const unsigned short* __restrict__ kT,
               const unsigned short* __restrict__ v,
               const unsigned short* __restrict__ qT,
               float* __restrict__ out) {
  __shared__ __align__(16) char smem[SMEM_SZ];
  const int tid  = threadIdx.x;
  const int lane = tid & 63;
  const int w    = tid >> 6;      // wave 0..7
  const int c15  = lane & 15;
  const int g    = lane >> 4;
  const int sh   = w >> 2;        // s-half 0/1 (rows sh*32..+31 of each tile)
  const int w2   = w & 3;         // t-quarter: rows w2*64..w2*64+63

  // XCD-local head mapping: xcd = bid&7 owns heads 4*xcd..4*xcd+3
  const int bid = blockIdx.x;
  const int bh  = (bid & 7) * 4 + ((bid >> 3) & 3);
  const int t0  = (bid >> 5) * 256;

  const unsigned short* kg = kT + (size_t)bh * 131072;
  const unsigned short* vg = v  + (size_t)bh * 131072;
  float*                og = out + (size_t)bh * 131072;

  // Q fragments: 4 t-groups x 2 kt ; row t = t0 + w2*64 + tg*16 + c15
  bf16x8 qf[4][2];
  {
    const unsigned short* qp0 = qT + (size_t)bh * 131072 +
                                (size_t)(t0 + w2 * 64 + c15) * 64 + 8 * g;
    #pragma unroll
    for (int tg = 0; tg < 4; ++tg) {
      qf[tg][0] = *(const bf16x8*)(qp0 + tg * 1024);
      qf[tg][1] = *(const bf16x8*)(qp0 + tg * 1024 + 32);
    }
  }

  // staging: 4 GLOAD16 per window per thread (2 tiles x {K,V})
  const int sr = tid >> 3, sb = tid & 7;
  const int ss = sb ^ (sr & 7);
  const unsigned short* kbase = kg + sr * 64 + ss * 8;     // + tile*4096
  const unsigned short* vbase = vg + sr * 2048 + ss * 8;   // + tile*64
  char* const slds = smem + tid * 16;

  f32x4 oacc[4][4];   // [tg][nc]: O^T col t=tg*16+c15, row c=nc*16+4g+r
  #pragma unroll
  for (int tg = 0; tg < 4; ++tg)
    #pragma unroll
    for (int nc = 0; nc < 4; ++nc) oacc[tg][nc] = (f32x4){0.f, 0.f, 0.f, 0.f};
  float lsum[4] = {0.f, 0.f, 0.f, 0.f};

  // ---- tile-phase helpers ----
  auto QK = [&](f32x4 (&acc)[4][2], char* kb) {
    #pragma unroll
    for (int kt = 0; kt < 2; ++kt)
      #pragma unroll
      for (int nt = 0; nt < 2; ++nt) {
        const int srow = sh * 32 + nt * 16 + c15;
        bf16x8 kf = *(bf16x8*)(kb + srow * 128 + (((kt * 4 + g) ^ (srow & 7)) * 16));
        #pragma unroll
        for (int tg = 0; tg < 4; ++tg)
          acc[tg][nt] = __builtin_amdgcn_mfma_f32_16x16x32_bf16(kf, qf[tg][kt], acc[tg][nt], 0, 0, 0);
      }
  };
  auto SM = [&](f32x4 (&acc)[4][2], bf16x8 (&pa)[4]) {
    #pragma unroll
    for (int tg = 0; tg < 4; ++tg) {
      unsigned W[4];
      #pragma unroll
      for (int nt = 0; nt < 2; ++nt) {
        float p0 = exp2_fast(acc[tg][nt][0]);
        float p1 = exp2_fast(acc[tg][nt][1]);
        float p2 = exp2_fast(acc[tg][nt][2]);
        float p3 = exp2_fast(acc[tg][nt][3]);
        lsum[tg] += (p0 + p1) + (p2 + p3);
        W[nt * 2]     = cvt_pk_bf16(p0, p1);
        W[nt * 2 + 1] = cvt_pk_bf16(p2, p3);
      }
      unsigned a0 = W[0], b0 = W[2], a1 = W[1], b1 = W[3];
      asm volatile("v_permlane32_swap_b32 %0, %1" : "+v"(a0), "+v"(b0));
      asm volatile("v_permlane32_swap_b32 %0, %1" : "+v"(a1), "+v"(b1));
      asm volatile("v_permlane16_swap_b32 %0, %1" : "+v"(a0), "+v"(b0));
      asm volatile("v_permlane16_swap_b32 %0, %1" : "+v"(a1), "+v"(b1));
      u32x4 fw = {a0, a1, b0, b1};
      pa[tg] = __builtin_bit_cast(bf16x8, fw);
    }
  };
  auto PV = [&](bf16x8 (&pa)[4], char* vb) {
    #pragma unroll
    for (int nc = 0; nc < 4; ++nc) {
      const int crow = nc * 16 + c15;
      bf16x8 vf = *(bf16x8*)(vb + crow * 128 + (((sh * 4 + g) ^ (crow & 7)) * 16));
      #pragma unroll
      for (int tg = 0; tg < 4; ++tg)
        oacc[tg][nc] = __builtin_amdgcn_mfma_f32_16x16x32_bf16(vf, pa[tg], oacc[tg][nc], 0, 0, 0);
    }
  };

  // window wn (tiles 2wn, 2wn+1) from bufset bs; prefetch window wn+1 -> bs^1
  auto window = [&](int bs, int wn, bool doIssue) {
    asm volatile("s_waitcnt vmcnt(0)" ::: "memory");   // stale by ~1 window
    __builtin_amdgcn_s_barrier();
    __builtin_amdgcn_sched_barrier(0);
    if (doIssue) {
      const unsigned short* kp = kbase + (size_t)(wn + 1) * 8192;
      const unsigned short* vp = vbase + (wn + 1) * 128;
      char* const ob = slds + (bs ^ 1) * WBS;
      GLOAD_LDS16(kp,        ob);            // K tile A
      GLOAD_LDS16(kp + 4096, ob + 8192);     // K tile B
      GLOAD_LDS16(vp,        ob + 16384);    // V tile A
      GLOAD_LDS16(vp + 64,   ob + 24576);    // V tile B
    }
    __builtin_amdgcn_sched_barrier(0);

    char* const base = smem + bs * WBS;
    f32x4 accA[4][2], accB[4][2];
    #pragma unroll
    for (int tg = 0; tg < 4; ++tg)
      #pragma unroll
      for (int nt = 0; nt < 2; ++nt) {
        accA[tg][nt] = (f32x4){0.f, 0.f, 0.f, 0.f};
        accB[tg][nt] = (f32x4){0.f, 0.f, 0.f, 0.f};
      }
    __builtin_amdgcn_s_setprio(1);
    QK(accA, base);
    QK(accB, base + 8192);
    __builtin_amdgcn_s_setprio(0);
    bf16x8 paA[4], paB[4];
    SM(accA, paA);
    __builtin_amdgcn_s_setprio(1);
    PV(paA, base + 16384);
    __builtin_amdgcn_s_setprio(0);
    SM(accB, paB);
    __builtin_amdgcn_s_setprio(1);
    PV(paB, base + 24576);
    __builtin_amdgcn_s_setprio(0);
  };

  // prologue: stage window 0 into bufset 0
  GLOAD_LDS16(kbase,        slds);
  GLOAD_LDS16(kbase + 4096, slds + 8192);
  GLOAD_LDS16(vbase,        slds + 16384);
  GLOAD_LDS16(vbase + 64,   slds + 24576);

  #pragma unroll 1
  for (int mi = 0; mi < 8; ++mi) {
    window(0, 2 * mi,     true);
    window(1, 2 * mi + 1, mi < 7);
  }

  // per-wave l over its s-half: reduce 4 g-copies -> uniform per c15
  #pragma unroll
  for (int tg = 0; tg < 4; ++tg) {
    lsum[tg] += __shfl_xor(lsum[tg], 16);
    lsum[tg] += __shfl_xor(lsum[tg], 32);
  }

  // ---- epilogue: combine s-halves via LDS ----
  __syncthreads();                       // all waves done with K/V buffers
  float* lsl = (float*)(smem + LSUM_OFF);
  if (lane < 16)
    #pragma unroll
    for (int tg = 0; tg < 4; ++tg) lsl[(w * 4 + tg) * 16 + c15] = lsum[tg];
  if (sh == 0) {
    float* ep = (float*)(smem + w2 * EP_W2);
    #pragma unroll
    for (int tg = 0; tg < 4; ++tg)
      #pragma unroll
      for (int nc = 0; nc < 4; ++nc)
        #pragma unroll
        for (int r = 0; r < 4; ++r)
          ep[(nc * 16 + 4 * g + r) * EP_STR + tg * 16 + c15] = oacc[tg][nc][r];
  }
  __syncthreads();
  if (sh == 1) {
    float invl[4];
    #pragma unroll
    for (int tg = 0; tg < 4; ++tg)
      invl[tg] = 1.0f / (lsum[tg] + lsl[(w2 * 4 + tg) * 16 + c15]);
    float* ep = (float*)(smem + w2 * EP_W2);
    float* ob = og + t0 + w2 * 64 + c15 + (size_t)(4 * g) * 2048;
    #pragma unroll
    for (int tg = 0; tg < 4; ++tg)
      #pragma unroll
      for (int nc = 0; nc < 4; ++nc)
        #pragma unroll
        for (int r = 0; r < 4; ++r) {
          float o = ep[(nc * 16 + 4 * g + r) * EP_STR + tg * 16 + c15] + oacc[tg][nc][r];
          ob[(size_t)(nc * 16 + r) * 2048 + tg * 16] = o * invl[tg];
        }
  }
}

// ---------------- fallback (round-1 kernel, self-converting) ----------------
#define LDS_K 0
#define LDS_V 8192
#define LDS_P 16384
#define LDS_TOTAL 27648

__global__ __launch_bounds__(256)
void attn_fwd(const float* __restrict__ qkv, const float* __restrict__ y,
              float* __restrict__ out) {
  __shared__ __align__(16) char smem[LDS_TOTAL];
  const int tid  = threadIdx.x;
  const int lane = tid & 63;
  const int w    = tid >> 6;
  const int c15  = lane & 15;
  const int g    = lane >> 4;
  const int bh = blockIdx.x >> 5;
  const int t0 = (blockIdx.x & 31) * 64;
  const float* qg = qkv + (size_t)bh * 64 * 2048;
  const float* kg = y   + (size_t)bh * 64 * 2048;
  float*       og = out + (size_t)bh * 64 * 2048;
  const float SC = 0.35355339059327373f;
  typedef __attribute__((ext_vector_type(4))) float f4;
  bf16x8 qf[2];
  {
    const int tq = t0 + w * 16 + c15;
    #pragma unroll
    for (int kt = 0; kt < 2; ++kt)
      #pragma unroll
      for (int j = 0; j < 8; ++j)
        qf[kt][j] = (short)f2bf(qg[(kt * 32 + 8 * g + j) * 2048 + tq] * SC);
  }
  f32x4 oacc[4];
  #pragma unroll
  for (int nc = 0; nc < 4; ++nc) oacc[nc] = (f32x4){0.f, 0.f, 0.f, 0.f};
  float m_run[4], l_run[4];
  #pragma unroll
  for (int r = 0; r < 4; ++r) { m_run[r] = -1e30f; l_run[r] = 0.f; }
  const int ks_row = tid & 63, ks_cb = tid >> 6;
  const int vs_c = tid >> 2, vs_j = tid & 3;
  for (int it = 0; it < 32; ++it) {
    const int s0 = it * 64;
    #pragma unroll
    for (int pass = 0; pass < 2; ++pass) {
      const int cblk = pass * 4 + ks_cb;
      bf16x8 pk;
      #pragma unroll
      for (int i = 0; i < 8; ++i)
        pk[i] = (short)f2bf(kg[(cblk * 8 + i) * 2048 + s0 + ks_row] * SC);
      *(bf16x8*)(smem + LDS_K + ks_row * 128 + ((cblk ^ (ks_row & 7)) * 16)) = pk;
    }
    #pragma unroll
    for (int pass = 0; pass < 2; ++pass) {
      const int sblk = pass * 4 + vs_j;
      const f4 a = *(const f4*)(kg + vs_c * 2048 + s0 + sblk * 8);
      const f4 b = *(const f4*)(kg + vs_c * 2048 + s0 + sblk * 8 + 4);
      bf16x8 pv;
      #pragma unroll
      for (int i = 0; i < 4; ++i) { pv[i] = (short)f2bf(a[i]); pv[4 + i] = (short)f2bf(b[i]); }
      *(bf16x8*)(smem + LDS_V + vs_c * 128 + ((sblk ^ (vs_c & 7)) * 16)) = pv;
    }
    __syncthreads();
    f32x4 accs[4];
    #pragma unroll
    for (int nt = 0; nt < 4; ++nt) accs[nt] = (f32x4){0.f, 0.f, 0.f, 0.f};
    #pragma unroll
    for (int kt = 0; kt < 2; ++kt)
      #pragma unroll
      for (int nt = 0; nt < 4; ++nt) {
        const int srow = nt * 16 + c15;
        bf16x8 kf = *(bf16x8*)(smem + LDS_K + srow * 128 +
                               (((kt * 4 + g) ^ (srow & 7)) * 16));
        accs[nt] = __builtin_amdgcn_mfma_f32_16x16x32_bf16(qf[kt], kf, accs[nt], 0, 0, 0);
      }
    float mt[4];
    #pragma unroll
    for (int r = 0; r < 4; ++r)
      mt[r] = fmaxf(fmaxf(accs[0][r], accs[1][r]), fmaxf(accs[2][r], accs[3][r]));
    #pragma unroll
    for (int off = 1; off <= 8; off <<= 1)
      #pragma unroll
      for (int r = 0; r < 4; ++r) mt[r] = fmaxf(mt[r], __shfl_xor(mt[r], off));
    float alpha[4];
    #pragma unroll
    for (int r = 0; r < 4; ++r) {
      float mn = fmaxf(m_run[r], mt[r]);
      alpha[r] = __expf(m_run[r] - mn);
      m_run[r] = mn;
    }
    float ls[4] = {0.f, 0.f, 0.f, 0.f};
    #pragma unroll
    for (int nt = 0; nt < 4; ++nt)
      #pragma unroll
      for (int r = 0; r < 4; ++r) {
        float p = __expf(accs[nt][r] - m_run[r]);
        accs[nt][r] = p;
        ls[r] += p;
      }
    #pragma unroll
    for (int off = 1; off <= 8; off <<= 1)
      #pragma unroll
      for (int r = 0; r < 4; ++r) ls[r] += __shfl_xor(ls[r], off);
    #pragma unroll
    for (int r = 0; r < 4; ++r) l_run[r] = l_run[r] * alpha[r] + ls[r];
    #pragma unroll
    for (int nc = 0; nc < 4; ++nc)
      #pragma unroll
      for (int r = 0; r < 4; ++r) oacc[nc][r] *= alpha[r];
    char* pb = smem + LDS_P + w * 2816;
    #pragma unroll
    for (int nt = 0; nt < 4; ++nt)
      #pragma unroll
      for (int r = 0; r < 4; ++r)
        *(unsigned short*)(pb + (4 * g + r) * 176 + (nt * 16 + c15) * 2) =
            f2bf(accs[nt][r]);
    __builtin_amdgcn_sched_barrier(0);
    #pragma unroll
    for (int kt = 0; kt < 2; ++kt) {
      bf16x8 pf = *(bf16x8*)(pb + c15 * 176 + (kt * 32 + 8 * g) * 2);
      #pragma unroll
      for (int nc = 0; nc < 4; ++nc) {
        const int crow = nc * 16 + c15;
        bf16x8 vf = *(bf16x8*)(smem + LDS_V + crow * 128 +
                               (((kt * 4 + g) ^ (crow & 7)) * 16));
        oacc[nc] = __builtin_amdgcn_mfma_f32_16x16x32_bf16(pf, vf, oacc[nc], 0, 0, 0);
      }
    }
    __syncthreads();
  }
  float inv_l[4];
  #pragma unroll
  for (int r = 0; r < 4; ++r) inv_l[r] = 1.0f / l_run[r];
  float* ep = (float*)smem;
  #pragma unroll
  for (int nc = 0; nc < 4; ++nc)
    #pragma unroll
    for (int r = 0; r < 4; ++r)
      ep[(nc * 16 + c15) * 68 + (w * 16 + 4 * g + r)] = oacc[nc][r] * inv_l[r];
  __syncthreads();
  #pragma unroll
  for (int itr = 0; itr < 4; ++itr) {
    int idx = itr * 256 + tid;
    int cc  = idx >> 4;
    int v4  = idx & 15;
    f4 o = *(f4*)(ep + cc * 68 + v4 * 4);
    *(f4*)(og + cc * 2048 + t0 + v4 * 4) = o;
  }
}

extern "C" void kernel_launch(void* const* d_in, const int* in_sizes, int n_in,
                              void* d_out, int out_size, void* d_ws, size_t ws_size,
                              hipStream_t stream) {
  const float* qkv = (const float*)d_in[0];
  const float* y   = (const float*)d_in[1];
  float*       out = (float*)d_out;
  if (ws_size < (size_t)25165824) {   // 3 x 8 MiB bf16 layouts
    attn_fwd<<<dim3(1024), dim3(256), 0, stream>>>(qkv, y, out);
    return;
  }
  unsigned short* kT = (unsigned short*)d_ws;
  unsigned short* vv = kT + 4194304;
  unsigned short* qT = kT + 8388608;
  prep<<<dim3(2048), dim3(256), 0, stream>>>(qkv, y, kT, vv, qT);
  attn_main<<<dim3(256), dim3(512), 0, stream>>>(kT, vv, qT, out);
}

// Round 12
// 53.397 us; speedup vs baseline: 1.0189x; 1.0189x over previous
//
#include <hip/hip_runtime.h>
#include <hip/hip_bf16.h>

// QKVAttentionLegacy: B*H=32, C=64, T=S=2048, fp32 in/out, channels-first.
// Round 12 = Round 7 verbatim (proven: 53.7 us total, absmax 3.9e-3).
// 2-tile windows, ONE raw s_barrier + stale vmcnt(0) per window; setprio
// intrinsics retained (they double as compiler code-motion fences keeping
// ds_reads below the barrier — removing them caused NaN in R9/R11).
// Swapped QK^T, reg-P via permlane swaps, O^T = V*P, grid 256, 512 thr.

typedef __attribute__((ext_vector_type(4))) float f32x4;
typedef __attribute__((ext_vector_type(8))) short bf16x8;
typedef __attribute__((ext_vector_type(4))) float float4_t;
typedef __attribute__((ext_vector_type(4))) unsigned u32x4;

__device__ __forceinline__ unsigned short f2bf(float f) {
  unsigned u = __builtin_bit_cast(unsigned, f);
  u += 0x7FFFu + ((u >> 16) & 1u);               // round-to-nearest-even
  return (unsigned short)(u >> 16);
}

__device__ __forceinline__ float exp2_fast(float x) {
  float r;
  asm("v_exp_f32 %0, %1" : "=v"(r) : "v"(x));
  return r;
}

__device__ __forceinline__ unsigned cvt_pk_bf16(float a, float b) {
  unsigned r;
  asm("v_cvt_pk_bf16_f32 %0, %1, %2" : "=v"(r) : "v"(a), "v"(b));
  return r;
}

#define GLOAD_LDS16(g, l) __builtin_amdgcn_global_load_lds(                 \
    (const __attribute__((address_space(1))) unsigned*)(g),                 \
    (__attribute__((address_space(3))) unsigned*)(l), 16, 0, 0)

// scale = 1/sqrt(sqrt(64)) per operand; sqrt(log2e) folded so S_mfma = S*log2e
#define SCL (0.35355339059327373f * 1.2011224087864498f)

// ---------------- pre-pass: f32 [bh][c][s] -> bf16 layouts ----------------
__global__ __launch_bounds__(256)
void prep(const float* __restrict__ qkv, const float* __restrict__ y,
          unsigned short* __restrict__ kT, unsigned short* __restrict__ v,
          unsigned short* __restrict__ qT) {
  __shared__ unsigned short tb[64][66];
  const int tid = threadIdx.x;
  const int isQ = blockIdx.x >> 10;
  const int b2  = blockIdx.x & 1023;
  const int bh  = b2 >> 5;
  const int s0  = (b2 & 31) * 64;
  const float* src = (isQ ? qkv : y) + (size_t)bh * 131072;

  const int c = tid >> 2, j = tid & 3;
  float fv[16];
  #pragma unroll
  for (int p = 0; p < 4; ++p) {
    float4_t a = *(const float4_t*)(src + c * 2048 + s0 + j * 16 + p * 4);
    #pragma unroll
    for (int i = 0; i < 4; ++i) fv[p * 4 + i] = a[i];
  }
  if (!isQ) {   // v: unscaled bf16, natural [c][s]
    bf16x8 u0, u1;
    #pragma unroll
    for (int i = 0; i < 8; ++i) { u0[i] = (short)f2bf(fv[i]); u1[i] = (short)f2bf(fv[8 + i]); }
    unsigned short* vp = v + (size_t)bh * 131072 + c * 2048 + s0 + j * 16;
    *(bf16x8*)(vp) = u0;
    *(bf16x8*)(vp + 8) = u1;
  }
  #pragma unroll
  for (int m = 0; m < 8; ++m) {
    unsigned lo = f2bf(fv[2 * m] * SCL);
    unsigned hi = f2bf(fv[2 * m + 1] * SCL);
    *(unsigned*)&tb[c][j * 16 + 2 * m] = lo | (hi << 16);
  }
  __syncthreads();

  const int srow = tid >> 2, i2 = tid & 3;
  unsigned short outv[16];
  #pragma unroll
  for (int m = 0; m < 16; ++m) outv[m] = tb[i2 * 16 + m][srow];
  unsigned short* dT = (isQ ? qT : kT) + (size_t)bh * 131072 +
                       (size_t)(s0 + srow) * 64 + i2 * 16;
  *(bf16x8*)(dT)     = *(bf16x8*)&outv[0];
  *(bf16x8*)(dT + 8) = *(bf16x8*)&outv[8];
}

// ---------------- main kernel: 2-tile windows, raw barriers ----------------
#define WBS 32768   // window bufset: K_A(8K) K_B(8K) V_A(8K) V_B(8K)

__global__ __launch_bounds__(512, 2)
void attn_main(const unsigned short* __restrict__ kT,
               const unsigned short* __restrict__ v,
               const unsigned short* __restrict__ qT,
               float* __restrict__ out) {
  __shared__ __align__(16) char smem[2 * WBS];
  const int tid  = threadIdx.x;
  const int lane = tid & 63;
  const int w    = tid >> 6;      // wave 0..7 -> t-rows w*32..w*32+31
  const int c15  = lane & 15;
  const int g    = lane >> 4;

  // XCD-local head mapping: xcd = bid&7 owns heads 4*xcd..4*xcd+3
  const int bid = blockIdx.x;
  const int bh  = (bid & 7) * 4 + ((bid >> 3) & 3);
  const int t0  = (bid >> 5) * 256;

  const unsigned short* kg = kT + (size_t)bh * 131072;
  const unsigned short* vg = v  + (size_t)bh * 131072;
  float*                og = out + (size_t)bh * 131072;

  // Q fragments: 2 t-groups x 2 kt ; row t = t0 + w*32 + tg*16 + c15
  bf16x8 qf[2][2];
  {
    const unsigned short* qp0 = qT + (size_t)bh * 131072 +
                                (size_t)(t0 + w * 32 + c15) * 64 + 8 * g;
    qf[0][0] = *(const bf16x8*)(qp0);
    qf[0][1] = *(const bf16x8*)(qp0 + 32);
    qf[1][0] = *(const bf16x8*)(qp0 + 1024);       // +16 rows
    qf[1][1] = *(const bf16x8*)(qp0 + 1024 + 32);
  }

  // staging: 4 GLOAD16 per window per thread (2 tiles x {K,V})
  const int sr = tid >> 3, sb = tid & 7;
  const int ss = sb ^ (sr & 7);
  const unsigned short* kbase = kg + sr * 64 + ss * 8;     // + tile*4096
  const unsigned short* vbase = vg + sr * 2048 + ss * 8;   // + tile*64
  char* const slds = smem + tid * 16;

  f32x4 oacc[2][4];
  #pragma unroll
  for (int tg = 0; tg < 2; ++tg)
    #pragma unroll
    for (int nc = 0; nc < 4; ++nc) oacc[tg][nc] = (f32x4){0.f, 0.f, 0.f, 0.f};
  float lsum[2] = {0.f, 0.f};

  // tile-phase helpers (all LDS offsets constant after inlining)
  auto QK = [&](f32x4 (&acc)[2][4], char* kb) {
    #pragma unroll
    for (int kt = 0; kt < 2; ++kt)
      #pragma unroll
      for (int nt = 0; nt < 4; ++nt) {
        const int srow = nt * 16 + c15;
        bf16x8 kf = *(bf16x8*)(kb + srow * 128 + (((kt * 4 + g) ^ (srow & 7)) * 16));
        acc[0][nt] = __builtin_amdgcn_mfma_f32_16x16x32_bf16(kf, qf[0][kt], acc[0][nt], 0, 0, 0);
        acc[1][nt] = __builtin_amdgcn_mfma_f32_16x16x32_bf16(kf, qf[1][kt], acc[1][nt], 0, 0, 0);
      }
  };
  auto SM = [&](f32x4 (&acc)[2][4], bf16x8 (&pa)[2][2]) {
    #pragma unroll
    for (int tg = 0; tg < 2; ++tg) {
      unsigned W[8];
      #pragma unroll
      for (int nt = 0; nt < 4; ++nt) {
        float p0 = exp2_fast(acc[tg][nt][0]);
        float p1 = exp2_fast(acc[tg][nt][1]);
        float p2 = exp2_fast(acc[tg][nt][2]);
        float p3 = exp2_fast(acc[tg][nt][3]);
        lsum[tg] += (p0 + p1) + (p2 + p3);
        W[nt * 2]     = cvt_pk_bf16(p0, p1);
        W[nt * 2 + 1] = cvt_pk_bf16(p2, p3);
      }
      #pragma unroll
      for (int kt = 0; kt < 2; ++kt) {
        unsigned a0 = W[kt * 4 + 0], b0 = W[kt * 4 + 2];
        unsigned a1 = W[kt * 4 + 1], b1 = W[kt * 4 + 3];
        asm volatile("v_permlane32_swap_b32 %0, %1" : "+v"(a0), "+v"(b0));
        asm volatile("v_permlane32_swap_b32 %0, %1" : "+v"(a1), "+v"(b1));
        asm volatile("v_permlane16_swap_b32 %0, %1" : "+v"(a0), "+v"(b0));
        asm volatile("v_permlane16_swap_b32 %0, %1" : "+v"(a1), "+v"(b1));
        u32x4 fw = {a0, a1, b0, b1};
        pa[tg][kt] = __builtin_bit_cast(bf16x8, fw);
      }
    }
  };
  auto PV = [&](bf16x8 (&pa)[2][2], char* vb) {
    #pragma unroll
    for (int kt = 0; kt < 2; ++kt)
      #pragma unroll
      for (int nc = 0; nc < 4; ++nc) {
        const int crow = nc * 16 + c15;
        bf16x8 vf = *(bf16x8*)(vb + crow * 128 + (((kt * 4 + g) ^ (crow & 7)) * 16));
        oacc[0][nc] = __builtin_amdgcn_mfma_f32_16x16x32_bf16(vf, pa[0][kt], oacc[0][nc], 0, 0, 0);
        oacc[1][nc] = __builtin_amdgcn_mfma_f32_16x16x32_bf16(vf, pa[1][kt], oacc[1][nc], 0, 0, 0);
      }
  };

  // window wn (tiles 2wn, 2wn+1) from bufset bs; prefetch window wn+1 -> bs^1
  auto window = [&](int bs, int wn, bool doIssue) {
    asm volatile("s_waitcnt vmcnt(0)" ::: "memory");   // stale by ~1 window
    __builtin_amdgcn_s_barrier();                      // all waves: W_wn landed,
    __builtin_amdgcn_sched_barrier(0);                 // W_{wn-1} fully read
    if (doIssue) {
      const unsigned short* kp = kbase + (size_t)(wn + 1) * 8192;
      const unsigned short* vp = vbase + (wn + 1) * 128;
      char* const ob = slds + (bs ^ 1) * WBS;
      GLOAD_LDS16(kp,        ob);            // K tile A
      GLOAD_LDS16(kp + 4096, ob + 8192);     // K tile B
      GLOAD_LDS16(vp,        ob + 16384);    // V tile A
      GLOAD_LDS16(vp + 64,   ob + 24576);    // V tile B
    }
    __builtin_amdgcn_sched_barrier(0);

    char* const base = smem + bs * WBS;
    f32x4 accA[2][4], accB[2][4];
    #pragma unroll
    for (int tg = 0; tg < 2; ++tg)
      #pragma unroll
      for (int nt = 0; nt < 4; ++nt) {
        accA[tg][nt] = (f32x4){0.f, 0.f, 0.f, 0.f};
        accB[tg][nt] = (f32x4){0.f, 0.f, 0.f, 0.f};
      }
    __builtin_amdgcn_s_setprio(1);
    QK(accA, base);
    QK(accB, base + 8192);
    __builtin_amdgcn_s_setprio(0);
    bf16x8 paA[2][2], paB[2][2];
    SM(accA, paA);
    __builtin_amdgcn_s_setprio(1);
    PV(paA, base + 16384);
    __builtin_amdgcn_s_setprio(0);
    SM(accB, paB);
    __builtin_amdgcn_s_setprio(1);
    PV(paB, base + 24576);
    __builtin_amdgcn_s_setprio(0);
  };

  // prologue: stage window 0 into bufset 0
  GLOAD_LDS16(kbase,        slds);
  GLOAD_LDS16(kbase + 4096, slds + 8192);
  GLOAD_LDS16(vbase,        slds + 16384);
  GLOAD_LDS16(vbase + 64,   slds + 24576);

  #pragma unroll 1
  for (int mi = 0; mi < 8; ++mi) {
    window(0, 2 * mi,     true);
    window(1, 2 * mi + 1, mi < 7);
  }

  // row sums: reduce 4 g-copies (lanes c15, +16, +32, +48)
  #pragma unroll
  for (int tg = 0; tg < 2; ++tg) {
    lsum[tg] += __shfl_xor(lsum[tg], 16);
    lsum[tg] += __shfl_xor(lsum[tg], 32);
  }
  const float invl0 = 1.0f / lsum[0];
  const float invl1 = 1.0f / lsum[1];

  // epilogue: per-lane scatter, 16-lane runs of consecutive t (64B sectors)
  float* ob = og + t0 + w * 32 + c15 + (size_t)(4 * g) * 2048;
  #pragma unroll
  for (int nc = 0; nc < 4; ++nc)
    #pragma unroll
    for (int r = 0; r < 4; ++r) {
      ob[(size_t)(nc * 16 + r) * 2048]      = oacc[0][nc][r] * invl0;
      ob[(size_t)(nc * 16 + r) * 2048 + 16] = oacc[1][nc][r] * invl1;
    }
}

// ---------------- fallback (round-1 kernel, self-converting) ----------------
#define LDS_K 0
#define LDS_V 8192
#define LDS_P 16384
#define LDS_TOTAL 27648

__global__ __launch_bounds__(256)
void attn_fwd(const float* __restrict__ qkv, const float* __restrict__ y,
              float* __restrict__ out) {
  __shared__ __align__(16) char smem[LDS_TOTAL];
  const int tid  = threadIdx.x;
  const int lane = tid & 63;
  const int w    = tid >> 6;
  const int c15  = lane & 15;
  const int g    = lane >> 4;
  const int bh = blockIdx.x >> 5;
  const int t0 = (blockIdx.x & 31) * 64;
  const float* qg = qkv + (size_t)bh * 64 * 2048;
  const float* kg = y   + (size_t)bh * 64 * 2048;
  float*       og = out + (size_t)bh * 64 * 2048;
  const float SC = 0.35355339059327373f;
  typedef __attribute__((ext_vector_type(4))) float f4;
  bf16x8 qf[2];
  {
    const int tq = t0 + w * 16 + c15;
    #pragma unroll
    for (int kt = 0; kt < 2; ++kt)
      #pragma unroll
      for (int j = 0; j < 8; ++j)
        qf[kt][j] = (short)f2bf(qg[(kt * 32 + 8 * g + j) * 2048 + tq] * SC);
  }
  f32x4 oacc[4];
  #pragma unroll
  for (int nc = 0; nc < 4; ++nc) oacc[nc] = (f32x4){0.f, 0.f, 0.f, 0.f};
  float m_run[4], l_run[4];
  #pragma unroll
  for (int r = 0; r < 4; ++r) { m_run[r] = -1e30f; l_run[r] = 0.f; }
  const int ks_row = tid & 63, ks_cb = tid >> 6;
  const int vs_c = tid >> 2, vs_j = tid & 3;
  for (int it = 0; it < 32; ++it) {
    const int s0 = it * 64;
    #pragma unroll
    for (int pass = 0; pass < 2; ++pass) {
      const int cblk = pass * 4 + ks_cb;
      bf16x8 pk;
      #pragma unroll
      for (int i = 0; i < 8; ++i)
        pk[i] = (short)f2bf(kg[(cblk * 8 + i) * 2048 + s0 + ks_row] * SC);
      *(bf16x8*)(smem + LDS_K + ks_row * 128 + ((cblk ^ (ks_row & 7)) * 16)) = pk;
    }
    #pragma unroll
    for (int pass = 0; pass < 2; ++pass) {
      const int sblk = pass * 4 + vs_j;
      const f4 a = *(const f4*)(kg + vs_c * 2048 + s0 + sblk * 8);
      const f4 b = *(const f4*)(kg + vs_c * 2048 + s0 + sblk * 8 + 4);
      bf16x8 pv;
      #pragma unroll
      for (int i = 0; i < 4; ++i) { pv[i] = (short)f2bf(a[i]); pv[4 + i] = (short)f2bf(b[i]); }
      *(bf16x8*)(smem + LDS_V + vs_c * 128 + ((sblk ^ (vs_c & 7)) * 16)) = pv;
    }
    __syncthreads();
    f32x4 accs[4];
    #pragma unroll
    for (int nt = 0; nt < 4; ++nt) accs[nt] = (f32x4){0.f, 0.f, 0.f, 0.f};
    #pragma unroll
    for (int kt = 0; kt < 2; ++kt)
      #pragma unroll
      for (int nt = 0; nt < 4; ++nt) {
        const int srow = nt * 16 + c15;
        bf16x8 kf = *(bf16x8*)(smem + LDS_K + srow * 128 +
                               (((kt * 4 + g) ^ (srow & 7)) * 16));
        accs[nt] = __builtin_amdgcn_mfma_f32_16x16x32_bf16(qf[kt], kf, accs[nt], 0, 0, 0);
      }
    float mt[4];
    #pragma unroll
    for (int r = 0; r < 4; ++r)
      mt[r] = fmaxf(fmaxf(accs[0][r], accs[1][r]), fmaxf(accs[2][r], accs[3][r]));
    #pragma unroll
    for (int off = 1; off <= 8; off <<= 1)
      #pragma unroll
      for (int r = 0; r < 4; ++r) mt[r] = fmaxf(mt[r], __shfl_xor(mt[r], off));
    float alpha[4];
    #pragma unroll
    for (int r = 0; r < 4; ++r) {
      float mn = fmaxf(m_run[r], mt[r]);
      alpha[r] = __expf(m_run[r] - mn);
      m_run[r] = mn;
    }
    float ls[4] = {0.f, 0.f, 0.f, 0.f};
    #pragma unroll
    for (int nt = 0; nt < 4; ++nt)
      #pragma unroll
      for (int r = 0; r < 4; ++r) {
        float p = __expf(accs[nt][r] - m_run[r]);
        accs[nt][r] = p;
        ls[r] += p;
      }
    #pragma unroll
    for (int off = 1; off <= 8; off <<= 1)
      #pragma unroll
      for (int r = 0; r < 4; ++r) ls[r] += __shfl_xor(ls[r], off);
    #pragma unroll
    for (int r = 0; r < 4; ++r) l_run[r] = l_run[r] * alpha[r] + ls[r];
    #pragma unroll
    for (int nc = 0; nc < 4; ++nc)
      #pragma unroll
      for (int r = 0; r < 4; ++r) oacc[nc][r] *= alpha[r];
    char* pb = smem + LDS_P + w * 2816;
    #pragma unroll
    for (int nt = 0; nt < 4; ++nt)
      #pragma unroll
      for (int r = 0; r < 4; ++r)
        *(unsigned short*)(pb + (4 * g + r) * 176 + (nt * 16 + c15) * 2) =
            f2bf(accs[nt][r]);
    __builtin_amdgcn_sched_barrier(0);
    #pragma unroll
    for (int kt = 0; kt < 2; ++kt) {
      bf16x8 pf = *(bf16x8*)(pb + c15 * 176 + (kt * 32 + 8 * g) * 2);
      #pragma unroll
      for (int nc = 0; nc < 4; ++nc) {
        const int crow = nc * 16 + c15;
        bf16x8 vf = *(bf16x8*)(smem + LDS_V + crow * 128 +
                               (((kt * 4 + g) ^ (crow & 7)) * 16));
        oacc[nc] = __builtin_amdgcn_mfma_f32_16x16x32_bf16(pf, vf, oacc[nc], 0, 0, 0);
      }
    }
    __syncthreads();
  }
  float inv_l[4];
  #pragma unroll
  for (int r = 0; r < 4; ++r) inv_l[r] = 1.0f / l_run[r];
  float* ep = (float*)smem;
  #pragma unroll
  for (int nc = 0; nc < 4; ++nc)
    #pragma unroll
    for (int r = 0; r < 4; ++r)
      ep[(nc * 16 + c15) * 68 + (w * 16 + 4 * g + r)] = oacc[nc][r] * inv_l[r];
  __syncthreads();
  #pragma unroll
  for (int itr = 0; itr < 4; ++itr) {
    int idx = itr * 256 + tid;
    int cc  = idx >> 4;
    int v4  = idx & 15;
    f4 o = *(f4*)(ep + cc * 68 + v4 * 4);
    *(f4*)(og + cc * 2048 + t0 + v4 * 4) = o;
  }
}

extern "C" void kernel_launch(void* const* d_in, const int* in_sizes, int n_in,
                              void* d_out, int out_size, void* d_ws, size_t ws_size,
                              hipStream_t stream) {
  const float* qkv = (const float*)d_in[0];
  const float* y   = (const float*)d_in[1];
  float*       out = (float*)d_out;
  if (ws_size < (size_t)25165824) {   // 3 x 8 MiB bf16 layouts
    attn_fwd<<<dim3(1024), dim3(256), 0, stream>>>(qkv, y, out);
    return;
  }
  unsigned short* kT = (unsigned short*)d_ws;
  unsigned short* vv = kT + 4194304;
  unsigned short* qT = kT + 8388608;
  prep<<<dim3(2048), dim3(256), 0, stream>>>(qkv, y, kT, vv, qT);
  attn_main<<<dim3(256), dim3(512), 0, stream>>>(kT, vv, qT, out);
}